// Round 5
// baseline (220.902 us; speedup 1.0000x reference)
//
#include <hip/hip_runtime.h>
#include <math.h>

// (B,T,D) = (32, 2048, 512), fp32 in, fp32 out.
constexpr int B = 32;
constexpr int T = 2048;
constexpr int D = 512;

constexpr int C1 = 32;            // K1: chunks over T (1024 blocks)
constexpr int R1 = T / C1;        // 64 rows per K1 block
constexpr int C2 = 32;            // K2: blocks per batch
constexpr int RPB = T / C2;       // 64 rows per K2 block
constexpr int RW = 4;             // rows per chunk (per wave inner step)
constexpr int NCHUNK = RPB / (4 * RW);  // 4 chunks per wave (4 waves/block)
constexpr int NPART = C2;         // 32 block-partials per batch
constexpr int KSPLIT = 4;         // K3: blocks per batch (column split)

// ---------------- K1: column sums via global f32 atomics ----------------
// Each block LDS-reduces its 64-row chunk, then atomicAdds the 512-float
// partial into s[b][*]. s is zeroed by a 64 KB memset before this kernel.
// Replaces the P1 round-trip: K2 no longer re-reads 64 KB of partials per
// block (was 64 MB aggregate L2 traffic + a 32-deep loop + a barrier).
__global__ __launch_bounds__(256) void colsum_part(const float* __restrict__ x,
                                                   float* __restrict__ s) {
    const int b = blockIdx.x, c = blockIdx.y;
    const int d4 = threadIdx.x & 127;      // float4 column
    const int rp = threadIdx.x >> 7;       // row parity
    const float4* xp = (const float4*)x + ((size_t)(b * T + c * R1) * D >> 2)
                       + (size_t)rp * (D / 4) + d4;
    float4 acc = {0.f, 0.f, 0.f, 0.f};
    #pragma unroll 8
    for (int i = 0; i < R1 / 2; ++i) {
        float4 v = xp[(size_t)i * (D / 2)];
        acc.x += v.x; acc.y += v.y; acc.z += v.z; acc.w += v.w;
    }
    __shared__ float4 lds[128];
    if (rp == 1) lds[d4] = acc;
    __syncthreads();
    if (rp == 0) {
        float4 o = lds[d4];
        acc.x += o.x; acc.y += o.y; acc.z += o.z; acc.w += o.w;
        float* sp = s + (size_t)b * D + d4 * 4;
        atomicAdd(sp + 0, acc.x);
        atomicAdd(sp + 1, acc.y);
        atomicAdd(sp + 2, acc.z);
        atomicAdd(sp + 3, acc.w);
    }
}

// ---------------- K2: direct-s + online softmax-pool over 64 rows -------------
// Phase 1 is now two 16-B L2-hot loads per thread (each thread reads its own
// s fragment) — no LDS staging, no barrier. The chunk-0 x prefetch and the s
// loads pipeline freely into phase 2.
__global__ __launch_bounds__(256) void fused_pool(const float* __restrict__ x,
                                                  const float* __restrict__ s,
                                                  float* __restrict__ Mp,
                                                  float* __restrict__ Sp,
                                                  float* __restrict__ Op) {
    const int b = blockIdx.x, c = blockIdx.y;
    const int tid = threadIdx.x, wid = tid >> 6, lane = tid & 63;

    __shared__ float  mred[4], sred[4];
    __shared__ float4 Obuf[4][D / 4];    // 8 KB

    // --- Phase 0: issue chunk-0 x loads first ---
    const int t0 = c * RPB + wid * (NCHUNK * RW);    // wave owns 16 contiguous rows
    const float4* xr = (const float4*)(x + ((size_t)b * T + t0) * D) + lane * 2;
    float4 X0[RW], X1[RW];
    #pragma unroll
    for (int r = 0; r < RW; ++r) { X0[r] = xr[0]; X1[r] = xr[1]; xr += D / 4; }

    // --- Phase 1: direct s loads (2 KB per batch, L2/IF$-hot) ---
    const float4* sg = (const float4*)(s + (size_t)b * D);
    const float4 s0 = sg[lane * 2];
    const float4 s1 = sg[lane * 2 + 1];

    // --- Phase 2: online softmax + pool over NCHUNK chunks of RW rows ---
    float m = -INFINITY, ssum = 0.f;
    float4 O0 = {0.f,0.f,0.f,0.f}, O1 = {0.f,0.f,0.f,0.f};

    #pragma unroll
    for (int ch = 0; ch < NCHUNK; ++ch) {
        // stash current chunk, issue next chunk's loads (double-buffer in regs)
        float4 Y0[RW], Y1[RW];
        #pragma unroll
        for (int r = 0; r < RW; ++r) { Y0[r] = X0[r]; Y1[r] = X1[r]; }
        if (ch + 1 < NCHUNK) {
            #pragma unroll
            for (int r = 0; r < RW; ++r) { X0[r] = xr[0]; X1[r] = xr[1]; xr += D / 4; }
        }

        // dots: a_r = x_r . (s - x_r), partial over this thread's 8 cols
        float a[RW];
        #pragma unroll
        for (int r = 0; r < RW; ++r) {
            float t;
            t =      Y0[r].x * (s0.x - Y0[r].x);
            t = fmaf(Y0[r].y,  s0.y - Y0[r].y, t);
            t = fmaf(Y0[r].z,  s0.z - Y0[r].z, t);
            t = fmaf(Y0[r].w,  s0.w - Y0[r].w, t);
            t = fmaf(Y1[r].x,  s1.x - Y1[r].x, t);
            t = fmaf(Y1[r].y,  s1.y - Y1[r].y, t);
            t = fmaf(Y1[r].z,  s1.z - Y1[r].z, t);
            t = fmaf(Y1[r].w,  s1.w - Y1[r].w, t);
            a[r] = t;
        }
        #pragma unroll
        for (int off = 1; off < 64; off <<= 1) {
            #pragma unroll
            for (int r = 0; r < RW; ++r) a[r] += __shfl_xor(a[r], off, 64);
        }

        // online update: running max m, scaled sum ssum, pooled O
        const float mc = fmaxf(fmaxf(a[0], a[1]), fmaxf(a[2], a[3]));
        const float mn = fmaxf(m, mc);
        const float f  = __expf(m - mn);       // == 0 on first chunk (m = -inf)
        float e[RW], es = 0.f;
        #pragma unroll
        for (int r = 0; r < RW; ++r) { e[r] = __expf(a[r] - mn); es += e[r]; }
        ssum = fmaf(ssum, f, es);
        O0.x *= f; O0.y *= f; O0.z *= f; O0.w *= f;
        O1.x *= f; O1.y *= f; O1.z *= f; O1.w *= f;
        #pragma unroll
        for (int r = 0; r < RW; ++r) {
            O0.x = fmaf(e[r], Y0[r].x, O0.x); O0.y = fmaf(e[r], Y0[r].y, O0.y);
            O0.z = fmaf(e[r], Y0[r].z, O0.z); O0.w = fmaf(e[r], Y0[r].w, O0.w);
            O1.x = fmaf(e[r], Y1[r].x, O1.x); O1.y = fmaf(e[r], Y1[r].y, O1.y);
            O1.z = fmaf(e[r], Y1[r].z, O1.z); O1.w = fmaf(e[r], Y1[r].w, O1.w);
        }
        m = mn;
    }

    // --- Phase 3: in-block merge: 4 wave-partials -> one block partial ---
    if (lane == 0) { mred[wid] = m; sred[wid] = ssum; }
    __syncthreads();
    const float Mb = fmaxf(fmaxf(mred[0], mred[1]), fmaxf(mred[2], mred[3]));
    const float fw = __expf(m - Mb);                 // wave-uniform
    Obuf[wid][lane * 2]     = make_float4(O0.x * fw, O0.y * fw, O0.z * fw, O0.w * fw);
    Obuf[wid][lane * 2 + 1] = make_float4(O1.x * fw, O1.y * fw, O1.z * fw, O1.w * fw);
    __syncthreads();
    if (tid == 0) {
        float Sb = sred[0] * __expf(mred[0] - Mb) + sred[1] * __expf(mred[1] - Mb)
                 + sred[2] * __expf(mred[2] - Mb) + sred[3] * __expf(mred[3] - Mb);
        Mp[b * C2 + c] = Mb;
        Sp[b * C2 + c] = Sb;
    }
    if (tid < D / 4) {
        float4 v0 = Obuf[0][tid], v1 = Obuf[1][tid], v2 = Obuf[2][tid], v3 = Obuf[3][tid];
        float4 r;
        r.x = (v0.x + v1.x) + (v2.x + v3.x);
        r.y = (v0.y + v1.y) + (v2.y + v3.y);
        r.z = (v0.z + v1.z) + (v2.z + v3.z);
        r.w = (v0.w + v1.w) + (v2.w + v3.w);
        ((float4*)Op)[(size_t)(b * C2 + c) * (D / 4) + tid] = r;
    }
}

// ---------------- K3: merge 32 block-partials per batch -> out ----------------
// (verified round-4 version, unchanged: grid (B,4), per-wave 8-partial split)
__global__ __launch_bounds__(256) void merge_out(const float* __restrict__ Mp,
                                                 const float* __restrict__ Sp,
                                                 const float* __restrict__ Op,
                                                 float* __restrict__ out) {
    const int b = blockIdx.x, seg = blockIdx.y;       // seg: which 64-col slice
    const int tid = threadIdx.x, wid = tid >> 6, lane = tid & 63;
    __shared__ float fmerge[NPART];
    __shared__ float red[4];
    __shared__ float misc[1];
    __shared__ float2 part[4][64];                    // per-wave partials

    float Mc = -INFINITY, Sc = 0.f;
    if (tid < NPART) { Mc = Mp[b * NPART + tid]; Sc = Sp[b * NPART + tid]; }

    float mm = Mc;
    #pragma unroll
    for (int off = 1; off < 64; off <<= 1) mm = fmaxf(mm, __shfl_xor(mm, off, 64));
    if (lane == 0) red[wid] = mm;
    __syncthreads();
    const float Mg = fmaxf(fmaxf(red[0], red[1]), fmaxf(red[2], red[3]));
    __syncthreads();

    const float f = __expf(Mc - Mg);                  // 0 for tid >= NPART
    if (tid < NPART) fmerge[tid] = f;
    float fs = f * Sc;
    #pragma unroll
    for (int off = 1; off < 64; off <<= 1) fs += __shfl_xor(fs, off, 64);
    if (lane == 0) red[wid] = fs;
    __syncthreads();
    if (tid == 0) misc[0] = 1.0f / (red[0] + red[1] + red[2] + red[3]);
    __syncthreads();
    const float inv = misc[0];

    // wave `wid` accumulates partials [wid*8, wid*8+8) for its 64 float2 cols
    const int col = seg * 64 + lane;                  // float2 column in [0,256)
    float2 acc = {0.f, 0.f};
    const float2* op = (const float2*)Op + (size_t)b * NPART * (D / 2) + col;
    #pragma unroll
    for (int k = 0; k < 8; ++k) {
        const int cc = wid * 8 + k;
        const float fc = fmerge[cc];
        float2 v = op[(size_t)cc * (D / 2)];
        acc.x = fmaf(fc, v.x, acc.x);
        acc.y = fmaf(fc, v.y, acc.y);
    }
    part[wid][lane] = acc;
    __syncthreads();
    if (tid < 64) {
        float2 p0 = part[0][tid], p1 = part[1][tid], p2 = part[2][tid], p3 = part[3][tid];
        float2 r;
        r.x = ((p0.x + p1.x) + (p2.x + p3.x)) * inv;
        r.y = ((p0.y + p1.y) + (p2.y + p3.y)) * inv;
        ((float2*)out)[(size_t)b * (D / 2) + seg * 64 + tid] = r;
    }
}

extern "C" void kernel_launch(void* const* d_in, const int* in_sizes, int n_in,
                              void* d_out, int out_size, void* d_ws, size_t ws_size,
                              hipStream_t stream) {
    const float* x = (const float*)d_in[0];
    float* out = (float*)d_out;

    float* s  = (float*)d_ws;                      // B*D      = 64 KB
    float* Mp = s + (size_t)B * D;                 // B*C2     = 4 KB
    float* Sp = Mp + (size_t)B * C2;               // B*C2     = 4 KB
    float* Op = Sp + (size_t)B * C2;               // B*C2*D   = 2 MB

    hipMemsetAsync(s, 0, (size_t)B * D * sizeof(float), stream);
    colsum_part<<<dim3(B, C1), 256, 0, stream>>>(x, s);
    fused_pool<<<dim3(B, C2), 256, 0, stream>>>(x, s, Mp, Sp, Op);
    merge_out<<<dim3(B, KSPLIT), 256, 0, stream>>>(Mp, Sp, Op, out);
}

// Round 6
// 216.990 us; speedup vs baseline: 1.0180x; 1.0180x over previous
//
#include <hip/hip_runtime.h>
#include <math.h>

// (B,T,D) = (32, 2048, 512), fp32 in, fp32 out.
constexpr int B = 32;
constexpr int T = 2048;
constexpr int D = 512;

constexpr int C1 = 8;             // K1: chunks over T (256 blocks, 1/CU)
constexpr int R1 = T / C1;        // 256 rows per K1 block
constexpr int C2 = 32;            // K2: blocks per batch
constexpr int RPB = T / C2;       // 64 rows per K2 block
constexpr int RW = 4;             // rows per chunk (per wave inner step)
constexpr int NCHUNK = RPB / (4 * RW);  // 4 chunks per wave (4 waves/block)
constexpr int NPART = C2;         // 32 block-partials per batch
constexpr int KSPLIT = 4;         // K3: blocks per batch (column split)

// ---------------- K1: partial column sums (hierarchy depth 8) ----------------
// P1[b][c][d] = sum_{t in chunk c} x[b][t][d].  Grid (B,8): 256 blocks = one
// per CU, each streams 256 rows (512 KB). Same HBM bytes as before; K2's
// s-reduce shrinks 32 -> 8 iterations (64 -> 16 MB aggregate L2 reads).
__global__ __launch_bounds__(256) void colsum_part(const float* __restrict__ x,
                                                   float* __restrict__ P1) {
    const int b = blockIdx.x, c = blockIdx.y;
    const int d4 = threadIdx.x & 127;      // float4 column
    const int rp = threadIdx.x >> 7;       // row parity
    const float4* xp = (const float4*)x + ((size_t)(b * T + c * R1) * D >> 2)
                       + (size_t)rp * (D / 4) + d4;
    float4 acc = {0.f, 0.f, 0.f, 0.f};
    #pragma unroll 8
    for (int i = 0; i < R1 / 2; ++i) {
        float4 v = xp[(size_t)i * (D / 2)];
        acc.x += v.x; acc.y += v.y; acc.z += v.z; acc.w += v.w;
    }
    __shared__ float4 lds[128];
    if (rp == 1) lds[d4] = acc;
    __syncthreads();
    if (rp == 0) {
        float4 o = lds[d4];
        acc.x += o.x; acc.y += o.y; acc.z += o.z; acc.w += o.w;
        ((float4*)P1)[(size_t)(b * C1 + c) * (D / 4) + d4] = acc;
    }
}

// ---------------- K2: s-reduce(8) + online softmax-pool over 64 rows ----------
__global__ __launch_bounds__(256) void fused_pool(const float* __restrict__ x,
                                                  const float* __restrict__ P1,
                                                  float* __restrict__ Mp,
                                                  float* __restrict__ Sp,
                                                  float* __restrict__ Op) {
    const int b = blockIdx.x, c = blockIdx.y;
    const int tid = threadIdx.x, wid = tid >> 6, lane = tid & 63;

    __shared__ float  s_lds[D];          // 2 KB
    __shared__ float  mred[4], sred[4];
    __shared__ float4 Obuf[4][D / 4];    // 8 KB

    // --- Phase 0: issue chunk-0 x loads first (overlap with s-reduce below) ---
    const int t0 = c * RPB + wid * (NCHUNK * RW);    // wave owns 16 contiguous rows
    const float4* xr = (const float4*)(x + ((size_t)b * T + t0) * D) + lane * 2;
    float4 X0[RW], X1[RW];
    #pragma unroll
    for (int r = 0; r < RW; ++r) { X0[r] = xr[0]; X1[r] = xr[1]; xr += D / 4; }

    // --- Phase 1: in-block s-reduce over 8 partials: thread owns cols (2t,2t+1)
    {
        const float2* pp = (const float2*)(P1 + (size_t)b * C1 * D) + tid;
        float2 acc = {0.f, 0.f};
        #pragma unroll
        for (int k = 0; k < C1; ++k) {
            float2 v = pp[(size_t)k * (D / 2)];
            acc.x += v.x; acc.y += v.y;
        }
        ((float2*)s_lds)[tid] = acc;
    }
    __syncthreads();
    const float4 s0 = ((const float4*)s_lds)[lane * 2];
    const float4 s1 = ((const float4*)s_lds)[lane * 2 + 1];

    // --- Phase 2: online softmax + pool over NCHUNK chunks of RW rows ---
    float m = -INFINITY, ssum = 0.f;
    float4 O0 = {0.f,0.f,0.f,0.f}, O1 = {0.f,0.f,0.f,0.f};

    #pragma unroll
    for (int ch = 0; ch < NCHUNK; ++ch) {
        // stash current chunk, issue next chunk's loads (double-buffer in regs)
        float4 Y0[RW], Y1[RW];
        #pragma unroll
        for (int r = 0; r < RW; ++r) { Y0[r] = X0[r]; Y1[r] = X1[r]; }
        if (ch + 1 < NCHUNK) {
            #pragma unroll
            for (int r = 0; r < RW; ++r) { X0[r] = xr[0]; X1[r] = xr[1]; xr += D / 4; }
        }

        // dots: a_r = x_r . (s - x_r), partial over this thread's 8 cols
        float a[RW];
        #pragma unroll
        for (int r = 0; r < RW; ++r) {
            float t;
            t =      Y0[r].x * (s0.x - Y0[r].x);
            t = fmaf(Y0[r].y,  s0.y - Y0[r].y, t);
            t = fmaf(Y0[r].z,  s0.z - Y0[r].z, t);
            t = fmaf(Y0[r].w,  s0.w - Y0[r].w, t);
            t = fmaf(Y1[r].x,  s1.x - Y1[r].x, t);
            t = fmaf(Y1[r].y,  s1.y - Y1[r].y, t);
            t = fmaf(Y1[r].z,  s1.z - Y1[r].z, t);
            t = fmaf(Y1[r].w,  s1.w - Y1[r].w, t);
            a[r] = t;
        }
        #pragma unroll
        for (int off = 1; off < 64; off <<= 1) {
            #pragma unroll
            for (int r = 0; r < RW; ++r) a[r] += __shfl_xor(a[r], off, 64);
        }

        // online update: running max m, scaled sum ssum, pooled O
        const float mc = fmaxf(fmaxf(a[0], a[1]), fmaxf(a[2], a[3]));
        const float mn = fmaxf(m, mc);
        const float f  = __expf(m - mn);       // == 0 on first chunk (m = -inf)
        float e[RW], es = 0.f;
        #pragma unroll
        for (int r = 0; r < RW; ++r) { e[r] = __expf(a[r] - mn); es += e[r]; }
        ssum = fmaf(ssum, f, es);
        O0.x *= f; O0.y *= f; O0.z *= f; O0.w *= f;
        O1.x *= f; O1.y *= f; O1.z *= f; O1.w *= f;
        #pragma unroll
        for (int r = 0; r < RW; ++r) {
            O0.x = fmaf(e[r], Y0[r].x, O0.x); O0.y = fmaf(e[r], Y0[r].y, O0.y);
            O0.z = fmaf(e[r], Y0[r].z, O0.z); O0.w = fmaf(e[r], Y0[r].w, O0.w);
            O1.x = fmaf(e[r], Y1[r].x, O1.x); O1.y = fmaf(e[r], Y1[r].y, O1.y);
            O1.w = fmaf(e[r], Y1[r].w, O1.w); O1.z = fmaf(e[r], Y1[r].z, O1.z);
        }
        m = mn;
    }

    // --- Phase 3: in-block merge: 4 wave-partials -> one block partial ---
    if (lane == 0) { mred[wid] = m; sred[wid] = ssum; }
    __syncthreads();
    const float Mb = fmaxf(fmaxf(mred[0], mred[1]), fmaxf(mred[2], mred[3]));
    const float fw = __expf(m - Mb);                 // wave-uniform
    Obuf[wid][lane * 2]     = make_float4(O0.x * fw, O0.y * fw, O0.z * fw, O0.w * fw);
    Obuf[wid][lane * 2 + 1] = make_float4(O1.x * fw, O1.y * fw, O1.z * fw, O1.w * fw);
    __syncthreads();
    if (tid == 0) {
        float Sb = sred[0] * __expf(mred[0] - Mb) + sred[1] * __expf(mred[1] - Mb)
                 + sred[2] * __expf(mred[2] - Mb) + sred[3] * __expf(mred[3] - Mb);
        Mp[b * C2 + c] = Mb;
        Sp[b * C2 + c] = Sb;
    }
    if (tid < D / 4) {
        float4 v0 = Obuf[0][tid], v1 = Obuf[1][tid], v2 = Obuf[2][tid], v3 = Obuf[3][tid];
        float4 r;
        r.x = (v0.x + v1.x) + (v2.x + v3.x);
        r.y = (v0.y + v1.y) + (v2.y + v3.y);
        r.z = (v0.z + v1.z) + (v2.z + v3.z);
        r.w = (v0.w + v1.w) + (v2.w + v3.w);
        ((float4*)Op)[(size_t)(b * C2 + c) * (D / 4) + tid] = r;
    }
}

// ---------------- K3: merge 32 block-partials per batch -> out ----------------
// (verified round-4 version, unchanged: grid (B,4), per-wave 8-partial split)
__global__ __launch_bounds__(256) void merge_out(const float* __restrict__ Mp,
                                                 const float* __restrict__ Sp,
                                                 const float* __restrict__ Op,
                                                 float* __restrict__ out) {
    const int b = blockIdx.x, seg = blockIdx.y;       // seg: which 64-col slice
    const int tid = threadIdx.x, wid = tid >> 6, lane = tid & 63;
    __shared__ float fmerge[NPART];
    __shared__ float red[4];
    __shared__ float misc[1];
    __shared__ float2 part[4][64];                    // per-wave partials

    float Mc = -INFINITY, Sc = 0.f;
    if (tid < NPART) { Mc = Mp[b * NPART + tid]; Sc = Sp[b * NPART + tid]; }

    float mm = Mc;
    #pragma unroll
    for (int off = 1; off < 64; off <<= 1) mm = fmaxf(mm, __shfl_xor(mm, off, 64));
    if (lane == 0) red[wid] = mm;
    __syncthreads();
    const float Mg = fmaxf(fmaxf(red[0], red[1]), fmaxf(red[2], red[3]));
    __syncthreads();

    const float f = __expf(Mc - Mg);                  // 0 for tid >= NPART
    if (tid < NPART) fmerge[tid] = f;
    float fs = f * Sc;
    #pragma unroll
    for (int off = 1; off < 64; off <<= 1) fs += __shfl_xor(fs, off, 64);
    if (lane == 0) red[wid] = fs;
    __syncthreads();
    if (tid == 0) misc[0] = 1.0f / (red[0] + red[1] + red[2] + red[3]);
    __syncthreads();
    const float inv = misc[0];

    // wave `wid` accumulates partials [wid*8, wid*8+8) for its 64 float2 cols
    const int col = seg * 64 + lane;                  // float2 column in [0,256)
    float2 acc = {0.f, 0.f};
    const float2* op = (const float2*)Op + (size_t)b * NPART * (D / 2) + col;
    #pragma unroll
    for (int k = 0; k < 8; ++k) {
        const int cc = wid * 8 + k;
        const float fc = fmerge[cc];
        float2 v = op[(size_t)cc * (D / 2)];
        acc.x = fmaf(fc, v.x, acc.x);
        acc.y = fmaf(fc, v.y, acc.y);
    }
    part[wid][lane] = acc;
    __syncthreads();
    if (tid < 64) {
        float2 p0 = part[0][tid], p1 = part[1][tid], p2 = part[2][tid], p3 = part[3][tid];
        float2 r;
        r.x = ((p0.x + p1.x) + (p2.x + p3.x)) * inv;
        r.y = ((p0.y + p1.y) + (p2.y + p3.y)) * inv;
        ((float2*)out)[(size_t)b * (D / 2) + seg * 64 + tid] = r;
    }
}

extern "C" void kernel_launch(void* const* d_in, const int* in_sizes, int n_in,
                              void* d_out, int out_size, void* d_ws, size_t ws_size,
                              hipStream_t stream) {
    const float* x = (const float*)d_in[0];
    float* out = (float*)d_out;

    float* P1 = (float*)d_ws;                      // B*C1*D   = 512 KB
    float* Mp = P1 + (size_t)B * C1 * D;           // B*C2     = 4 KB
    float* Sp = Mp + (size_t)B * C2;               // B*C2     = 4 KB
    float* Op = Sp + (size_t)B * C2;               // B*C2*D   = 2 MB

    colsum_part<<<dim3(B, C1), 256, 0, stream>>>(x, P1);
    fused_pool<<<dim3(B, C2), 256, 0, stream>>>(x, P1, Mp, Sp, Op);
    merge_out<<<dim3(B, KSPLIT), 256, 0, stream>>>(Mp, Sp, Op, out);
}